// Round 14
// baseline (946.213 us; speedup 1.0000x reference)
//
#include <hip/hip_runtime.h>

#define DIM 1024
#define NHEADS 16
#define DH 64
#define BATCH 2
#define SEQ 2048

typedef float f32x4 __attribute__((ext_vector_type(4)));
typedef short s16x8 __attribute__((ext_vector_type(8)));
typedef short s16x4 __attribute__((ext_vector_type(4)));

__device__ __forceinline__ short f2bf(float f) {
    union { float f; unsigned u; } v; v.f = f;
    unsigned r = v.u + 0x7fffu + ((v.u >> 16) & 1u);   // RNE to bf16
    return (short)(r >> 16);
}

#if defined(__has_builtin)
#if __has_builtin(__builtin_amdgcn_cvt_pk_bf16_f32)
#define HAVE_PK_BF16 1
#endif
#endif
__device__ __forceinline__ unsigned f2bf_pk(float a, float b) {
#ifdef HAVE_PK_BF16
    typedef __bf16 bf16x2_t __attribute__((ext_vector_type(2)));
    bf16x2_t r = __builtin_amdgcn_cvt_pk_bf16_f32(a, b);
    return __builtin_bit_cast(unsigned, r);
#else
    return ((unsigned)(unsigned short)f2bf(b) << 16) | (unsigned short)f2bf(a);
#endif
}
__device__ __forceinline__ s16x4 pk4(float a, float b, float c, float d) {
    union { unsigned u[2]; s16x4 v; } x;
    x.u[0] = f2bf_pk(a, b); x.u[1] = f2bf_pk(c, d);
    return x.v;
}

#if defined(__has_builtin)
#if __has_builtin(__builtin_amdgcn_exp2f)
#define EXP2(x) __builtin_amdgcn_exp2f(x)
#endif
#endif
#ifndef EXP2
#define EXP2(x) exp2f(x)
#endif

__device__ __forceinline__ void gld16(const void* g, void* l) {
    __builtin_amdgcn_global_load_lds(
        (const __attribute__((address_space(1))) void*)g,
        (__attribute__((address_space(3))) void*)l, 16, 0, 0);
}

__device__ constexpr float QSCALE = 0.18033688011112042f;   // 0.125 * log2(e)

// ---------------- device-scope grid barrier (no cooperative API) ----------------
// release: __threadfence_system writes dirty L2 back to the coherent LLC (per-XCD L2s
// are NOT cross-coherent -- Guideline 16); arrive: device-scope atomicAdd (coherent,
// m20); spin: agent-scope atomic load (bypasses stale caches); acquire: second
// system fence invalidates stale lines before the next stage reads.
__device__ __forceinline__ void gbar(unsigned* cnt, unsigned target) {
    __syncthreads();
    __threadfence_system();
    if (threadIdx.x == 0) {
        atomicAdd(cnt, 1u);
        while (__hip_atomic_load(cnt, __ATOMIC_RELAXED, __HIP_MEMORY_SCOPE_AGENT) < target)
            __builtin_amdgcn_s_sleep(2);
    }
    __syncthreads();
    __threadfence_system();
}

// ---------------- stage 0: prep (virtual 256-thr block vb of 4096) ----------------
__device__ __forceinline__ void prep_body(int vb, int t,
    const float* __restrict__ X, short* __restrict__ Y,
    const float* __restrict__ Wq, const float* __restrict__ Wkv,
    const float* __restrict__ Wo, short* __restrict__ WT)
{
    if (vb < 2048) {
        const int i = (vb * 256 + t) * 8;
        float4 a = *(const float4*)(X + i);
        float4 b = *(const float4*)(X + i + 4);
        union { unsigned u[4]; s16x8 v; } o;
        o.u[0] = f2bf_pk(a.x, a.y); o.u[1] = f2bf_pk(a.z, a.w);
        o.u[2] = f2bf_pk(b.x, b.y); o.u[3] = f2bf_pk(b.z, b.w);
        *(s16x8*)(Y + i) = o.v;
    } else {
        const int i2 = vb - 2048;
        const int bx = i2 & 63, by = i2 >> 6;
        const int ng = bx * 64 + (t & 63);           // 0..4095
        const int k0 = (by * 4 + (t >> 6)) * 8;
        const float* W; int n, N;
        if (ng < 1024)      { W = Wq;  n = ng;        N = 1024; }
        else if (ng < 3072) { W = Wkv; n = ng - 1024; N = 2048; }
        else                { W = Wo;  n = ng - 3072; N = 1024; }
        float v[8];
#pragma unroll
        for (int j = 0; j < 8; ++j) v[j] = W[(size_t)(k0 + j) * N + n];
        union { unsigned u[4]; s16x8 s; } o;
        o.u[0] = f2bf_pk(v[0], v[1]); o.u[1] = f2bf_pk(v[2], v[3]);
        o.u[2] = f2bf_pk(v[4], v[5]); o.u[3] = f2bf_pk(v[6], v[7]);
        *(s16x8*)&WT[(size_t)ng * 1024 + k0] = o.s;
    }
}

// ---------------- stage 1: QKV GEMM, 512-thread 8-wave 128x128 tile ----------------
// slot in [0,768); r11 XCD-region remap (8 regions of 8m x 12n). Wave grid 2x4:
// wroff=(w>>2)*64, wcoff=(w&3)*32, acc[4][2] (32 VGPR).
__device__ __forceinline__ void qkv_body(int slot, int tid, short* As, short* Bs,
    const short* __restrict__ A, const short* __restrict__ Bt,
    const float* __restrict__ bq, const float* __restrict__ bkv,
    short* __restrict__ C)
{
    const int K = 1024;
    const int wave = tid >> 6, lane = tid & 63;
    const int col = lane & 15, quad = lane >> 4;
    const int x = slot & 7, i = slot >> 3;
    const int m0 = ((x & 3) * 8 + (i & 7)) * 128;
    const int n0 = ((x >> 2) * 12 + (i >> 3)) * 128;
    const int wroff = (wave >> 2) * 64;
    const int wcoff = (wave & 3) * 32;

    f32x4 acc[4][2];
#pragma unroll
    for (int mi = 0; mi < 4; ++mi)
#pragma unroll
        for (int ni = 0; ni < 2; ++ni) acc[mi][ni] = (f32x4){0.f, 0.f, 0.f, 0.f};

    const int srow = tid >> 2;           // 0..127
    const int scol = (tid & 3) * 8;
    const short* Ag = A  + (size_t)(m0 + srow) * K + scol;
    const short* Bg = Bt + (size_t)(n0 + srow) * K + scol;
    short* AsW = As + wave * 512;        // 16 rows x 32 shorts per wave
    short* BsW = Bs + wave * 512;

    for (int k0 = 0; k0 < K; k0 += 32) {
        __syncthreads();
        gld16(Ag + k0, AsW);
        gld16(Bg + k0, BsW);
        __syncthreads();

        s16x8 aA[4], bB[2];
#pragma unroll
        for (int mi = 0; mi < 4; ++mi)
            aA[mi] = *(const s16x8*)&As[(wroff + 16 * mi + col) * 32 + quad * 8];
#pragma unroll
        for (int ni = 0; ni < 2; ++ni)
            bB[ni] = *(const s16x8*)&Bs[(wcoff + 16 * ni + col) * 32 + quad * 8];
#pragma unroll
        for (int mi = 0; mi < 4; ++mi)
#pragma unroll
            for (int ni = 0; ni < 2; ++ni)
                acc[mi][ni] = __builtin_amdgcn_mfma_f32_16x16x32_bf16(aA[mi], bB[ni], acc[mi][ni], 0, 0, 0);
    }

#pragma unroll
    for (int ni = 0; ni < 2; ++ni) {
        const int nb = n0 + wcoff + 16 * ni + col;
        const float bias = (nb < 1024) ? bq[nb] : bkv[nb - 1024];
        const float scl  = (nb < 1024) ? QSCALE : 1.0f;
#pragma unroll
        for (int mi = 0; mi < 4; ++mi)
#pragma unroll
            for (int r = 0; r < 4; ++r) {
                const int gm = m0 + wroff + 16 * mi + quad * 4 + r;
                C[(size_t)gm * 3072 + nb] = f2bf((acc[mi][ni][r] + bias) * scl);
            }
    }
}

// ---------------- stage 2: V transpose (virtual 256-thr block vb of 1024) ----------------
__device__ __forceinline__ void tv_body(int vb, int t, short* L,
    const short* __restrict__ QKV, short* __restrict__ VtG)
{
    const int tok0 = (vb & 31) * 64;
    const int h = (vb >> 5) & 15, b = vb >> 9;
    const short* src = QKV + (size_t)(b * SEQ + tok0) * 3072 + 2048 + h * 64;
#pragma unroll
    for (int p = 0; p < 2; ++p) {
        int r = p * 32 + (t >> 3);
        *(s16x8*)&L[r * 72 + (t & 7) * 8] = *(const s16x8*)(src + (size_t)r * 3072 + (t & 7) * 8);
    }
    __syncthreads();
    short* dst = VtG + (size_t)(b * NHEADS + h) * 64 * SEQ + tok0;
#pragma unroll
    for (int p = 0; p < 2; ++p) {
        int u = p * 256 + t;
        int dv = u >> 3, c = (u & 7) * 8;
        s16x8 o;
#pragma unroll
        for (int j = 0; j < 8; ++j) o[j] = L[(c + j) * 72 + dv];
        *(s16x8*)(dst + (size_t)dv * SEQ + c) = o;
    }
}

// ---------------- stage 3: attention (v15 body verbatim; Lb = phys block) ----------------
__device__ __forceinline__ void attn_body(int Lb, int tid, short* Lds,
    const short* __restrict__ QKV, const short* __restrict__ VtG,
    short* __restrict__ O)
{
    const int xcd = Lb & 7, idx = Lb >> 3;
    const int pair = xcd * 4 + (idx >> 4);
    const int qt = idx & 15;
    const int h  = pair & 15;
    const int b  = pair >> 4;
    const int wave = tid >> 6;
    const int lane = tid & 63;
    const int col  = lane & 15;
    const int quad = lane >> 4;
    const int wq = wave & 3;
    const int kh = wave >> 2;

    short* KsB = Lds;                          // + cur*4608
    short* VtB = Lds + 2 * 64 * 72;            // + cur*4608
    short* PsW = Lds + 4 * 64 * 72 + wave * (32 * 40);

    const short* Qg = QKV + (size_t)(b * SEQ + qt * 128) * 3072 + h * DH;
    const short* Kg = QKV + (size_t)(b * SEQ) * 3072 + 1024 + h * DH;
    const short* VtRow = VtG + (size_t)(b * NHEADS + h) * 64 * SEQ;

    s16x8 aQ[2][2];
#pragma unroll
    for (int tq = 0; tq < 2; ++tq)
#pragma unroll
        for (int kq = 0; kq < 2; ++kq)
            aQ[tq][kq] = *(const s16x8*)(Qg + (size_t)(wq * 32 + 16 * tq + col) * 3072 + kq * 32 + quad * 8);

    f32x4 oa[4][2];
    float lsum[2] = {0.f, 0.f};
#pragma unroll
    for (int td = 0; td < 4; ++td)
#pragma unroll
        for (int tq = 0; tq < 2; ++tq) oa[td][tq] = (f32x4){0.f, 0.f, 0.f, 0.f};

    const int srow = tid >> 3;
    const int sc8  = (tid & 7) * 8;
    const short* KgS  = Kg + (size_t)srow * 3072 + sc8;
    const short* VtgS = VtRow + (size_t)srow * SEQ + sc8;
    s16x8 kx = *(const s16x8*)KgS;
    s16x8 vx = *(const s16x8*)VtgS;

    for (int kt = 0; kt < SEQ / 64; ++kt) {
        const int cur = kt & 1;
        *(s16x8*)&KsB[cur * 4608 + srow * 72 + sc8] = kx;
        *(s16x8*)&VtB[cur * 4608 + srow * 72 + sc8] = vx;
        {
            int nt = (kt + 1 < SEQ / 64) ? kt + 1 : kt;
            kx = *(const s16x8*)(KgS + (size_t)nt * 64 * 3072);
            vx = *(const s16x8*)(VtgS + (size_t)nt * 64);
        }
        __syncthreads();

        s16x8 aK[2][2];
#pragma unroll
        for (int tk = 0; tk < 2; ++tk)
#pragma unroll
            for (int kq = 0; kq < 2; ++kq)
                aK[tk][kq] = *(const s16x8*)&KsB[cur * 4608 + (kh * 32 + 16 * tk + col) * 72 + kq * 32 + quad * 8];
        f32x4 st[2][2];
        __builtin_amdgcn_s_setprio(1);
#pragma unroll
        for (int tk = 0; tk < 2; ++tk)
#pragma unroll
            for (int tq = 0; tq < 2; ++tq) {
                f32x4 a = (f32x4){0.f, 0.f, 0.f, 0.f};
                a = __builtin_amdgcn_mfma_f32_16x16x32_bf16(aK[tk][0], aQ[tq][0], a, 0, 0, 0);
                a = __builtin_amdgcn_mfma_f32_16x16x32_bf16(aK[tk][1], aQ[tq][1], a, 0, 0, 0);
                st[tk][tq] = a;
            }
        __builtin_amdgcn_s_setprio(0);

#pragma unroll
        for (int tk = 0; tk < 2; ++tk)
#pragma unroll
            for (int tq = 0; tq < 2; ++tq) {
                float p0 = EXP2(st[tk][tq][0]);
                float p1 = EXP2(st[tk][tq][1]);
                float p2 = EXP2(st[tk][tq][2]);
                float p3 = EXP2(st[tk][tq][3]);
                lsum[tq] += (p0 + p1) + (p2 + p3);
                *(s16x4*)&PsW[(16 * tq + col) * 40 + 16 * tk + quad * 4] = pk4(p0, p1, p2, p3);
            }
        asm volatile("s_waitcnt lgkmcnt(0)" ::: "memory");

        s16x8 bP[2];
#pragma unroll
        for (int tq = 0; tq < 2; ++tq)
            bP[tq] = *(const s16x8*)&PsW[(16 * tq + col) * 40 + quad * 8];
        __builtin_amdgcn_s_setprio(1);
#pragma unroll
        for (int td = 0; td < 4; ++td) {
            const int dv = 16 * td + col;
            s16x8 aV = *(const s16x8*)&VtB[cur * 4608 + dv * 72 + kh * 32 + quad * 8];
#pragma unroll
            for (int tq = 0; tq < 2; ++tq)
                oa[td][tq] = __builtin_amdgcn_mfma_f32_16x16x32_bf16(aV, bP[tq], oa[td][tq], 0, 0, 0);
        }
        __builtin_amdgcn_s_setprio(0);
    }

#pragma unroll
    for (int tq = 0; tq < 2; ++tq) {
        lsum[tq] += __shfl_xor(lsum[tq], 16);
        lsum[tq] += __shfl_xor(lsum[tq], 32);
    }

    __syncthreads();
    float* red  = (float*)Lds;
    float* redl = red + 4 * 64 * 36;
    if (wave >= 4) {
        const int slot = wave & 3;
#pragma unroll
        for (int td = 0; td < 4; ++td)
#pragma unroll
            for (int tq = 0; tq < 2; ++tq)
#pragma unroll
                for (int r = 0; r < 4; ++r)
                    red[slot * 2304 + (16 * td + quad * 4 + r) * 36 + 16 * tq + col] = oa[td][tq][r];
        if (quad == 0)
#pragma unroll
            for (int tq = 0; tq < 2; ++tq)
                redl[slot * 32 + 16 * tq + col] = lsum[tq];
    }
    __syncthreads();

    if (wave < 4) {
        const int slot = wq;
#pragma unroll
        for (int td = 0; td < 4; ++td)
#pragma unroll
            for (int tq = 0; tq < 2; ++tq)
#pragma unroll
                for (int r = 0; r < 4; ++r)
                    oa[td][tq][r] += red[slot * 2304 + (16 * td + quad * 4 + r) * 36 + 16 * tq + col];
        float inv[2];
#pragma unroll
        for (int tq = 0; tq < 2; ++tq) {
            lsum[tq] += redl[slot * 32 + 16 * tq + col];
            inv[tq] = 1.f / lsum[tq];
        }
        short* Og = O + (size_t)(b * SEQ + qt * 128 + wq * 32) * DIM + h * DH;
#pragma unroll
        for (int td = 0; td < 4; ++td)
#pragma unroll
            for (int tq = 0; tq < 2; ++tq)
                *(s16x4*)(Og + (size_t)(16 * tq + col) * DIM + 16 * td + quad * 4) =
                    pk4(oa[td][tq][0] * inv[tq], oa[td][tq][1] * inv[tq],
                        oa[td][tq][2] * inv[tq], oa[td][tq][3] * inv[tq]);
    }
}

// ---------------- stage 4: out GEMM, 256-thr 64x128 tile (2 per phys block) ----------------
__device__ __forceinline__ void out_body(int slot, int t, short* As, short* Bs,
    const short* __restrict__ A, const short* __restrict__ Bt,
    const float* __restrict__ bo, float* C)
{
    const int K = 1024;
    const int wave = t >> 6, lane = t & 63;
    const int col = lane & 15, quad = lane >> 4;
    const int m0 = (slot & 63) * 64;
    const int n0 = (slot >> 6) * 128;
    const int wcoff = wave * 32;

    f32x4 acc[4][2];
#pragma unroll
    for (int mi = 0; mi < 4; ++mi)
#pragma unroll
        for (int ni = 0; ni < 2; ++ni) acc[mi][ni] = (f32x4){0.f, 0.f, 0.f, 0.f};

    const int ldrowA = wave * 16 + (lane >> 2);
    const int ldrowB = wave * 32 + (lane >> 2);
    const int ldcol  = (lane & 3) * 8;
    const short* Ag = A  + (size_t)(m0 + ldrowA) * K + ldcol;
    const short* Bg = Bt + (size_t)(n0 + ldrowB) * K + ldcol;
    short* AsW = As + wave * 512;
    short* BsW = Bs + wave * 1024;

    for (int k0 = 0; k0 < K; k0 += 32) {
        __syncthreads();
        gld16(Ag + k0,          AsW);
        gld16(Bg + k0,          BsW);
        gld16(Bg + 16 * K + k0, BsW + 512);
        __syncthreads();

        s16x8 aA[4], bB[2];
#pragma unroll
        for (int mi = 0; mi < 4; ++mi)
            aA[mi] = *(const s16x8*)&As[(16 * mi + col) * 32 + quad * 8];
#pragma unroll
        for (int ni = 0; ni < 2; ++ni)
            bB[ni] = *(const s16x8*)&Bs[(wcoff + 16 * ni + col) * 32 + quad * 8];
#pragma unroll
        for (int mi = 0; mi < 4; ++mi)
#pragma unroll
            for (int ni = 0; ni < 2; ++ni)
                acc[mi][ni] = __builtin_amdgcn_mfma_f32_16x16x32_bf16(aA[mi], bB[ni], acc[mi][ni], 0, 0, 0);
    }

#pragma unroll
    for (int ni = 0; ni < 2; ++ni) {
        const int gn = n0 + wcoff + 16 * ni + col;
        const float bias = bo[gn];
#pragma unroll
        for (int mi = 0; mi < 4; ++mi)
#pragma unroll
            for (int r = 0; r < 4; ++r) {
                const int gm = m0 + 16 * mi + quad * 4 + r;
                C[(size_t)gm * DIM + gn] = acc[mi][ni][r] + bias;
            }
    }
}

// ---------------- fused pipeline: one REGULAR kernel + hand-rolled grid barriers ----------
// 512 blocks x 512 thr; co-residency guaranteed: LDS 57,344 B -> 2 blocks/CU (empirically
// demonstrated by the standalone attn at identical resources), 2 x 256 CU = 512.
__global__ __launch_bounds__(512, 4) void fused_mha(
    const float* __restrict__ q, const float* __restrict__ Wq,
    const float* __restrict__ bq, const float* __restrict__ Wkv,
    const float* __restrict__ bkv, const float* __restrict__ Wo,
    const float* __restrict__ bo,
    short* __restrict__ qb, short* __restrict__ WT,
    short* __restrict__ QKVbuf, short* VtG,
    short* __restrict__ AObuf, float* out, unsigned* bar)
{
    __shared__ __align__(16) short Lds[28672];   // 57,344 B arena, reused per stage

    const int p   = blockIdx.x;      // 0..511
    const int tid = threadIdx.x;     // 0..511
    const int half = tid >> 8;       // 0/1
    const int t    = tid & 255;

    // stage 0: prep (4096 virtual 256-thr blocks; 4 sweeps x 2 halves)
#pragma unroll
    for (int s = 0; s < 4; ++s)
        prep_body(s * 1024 + p * 2 + half, t, q, qb, Wq, Wkv, Wo, WT);
    gbar(bar + 0, 512);

    // stage 1: QKV GEMM (768 full-block 128x128 tiles; 2 sweeps)
    for (int sw = 0; sw < 2; ++sw) {
        const int slot = sw * 512 + p;
        if (slot < 768)
            qkv_body(slot, tid, Lds, Lds + 4096, qb, WT, bq, bkv, QKVbuf);
    }
    gbar(bar + 1, 512);

    // stage 2: V transpose (1024 virtual 256-thr blocks; 2 halves, exact)
    tv_body(p * 2 + half, t, Lds + half * 4608, QKVbuf, VtG);
    gbar(bar + 2, 512);

    // stage 3: attention (1:1, v15 structure -- measured 56us standalone)
    attn_body(p, tid, Lds, QKVbuf, VtG, AObuf);
    gbar(bar + 3, 512);

    // stage 4: out GEMM (512 virtual 256-thr 64x128 tiles; p<256 host 2 each)
    if (p < 256)
        out_body(p * 2 + half, t, Lds + half * 6144, Lds + half * 6144 + 2048,
                 AObuf, WT + (size_t)3072 * 1024, bo, out);
}

extern "C" void kernel_launch(void* const* d_in, const int* in_sizes, int n_in,
                              void* d_out, int out_size, void* d_ws, size_t ws_size,
                              hipStream_t stream)
{
    const float* q   = (const float*)d_in[0];
    const float* Wq  = (const float*)d_in[1];
    const float* bq  = (const float*)d_in[2];
    const float* Wkv = (const float*)d_in[3];
    const float* bkv = (const float*)d_in[4];
    const float* Wo  = (const float*)d_in[5];
    const float* bo  = (const float*)d_in[6];
    float* out = (float*)d_out;

    const int M = BATCH * SEQ;   // 4096

    // ws (48 MB): qb 8 | WT 8 | QKV 24 | AO 8.  VtG (8 MB) lives in d_out [0,8MB)
    // (dead before stage 4 overwrites d_out). Barrier counters live at d_out+12MB:
    // untouched until stage 4 (post-last-barrier) writes; re-zeroed by the memset
    // below on every launch (captured into the graph).
    short* qb     = (short*)d_ws;
    short* WT     = qb     + (size_t)M * DIM;
    short* QKVbuf = WT     + (size_t)4096 * DIM;
    short* AObuf  = QKVbuf + (size_t)M * 3 * DIM;
    short* VtG    = (short*)d_out;
    unsigned* bar = (unsigned*)((char*)d_out + (size_t)12 * 1024 * 1024);

    hipMemsetAsync(bar, 0, 64, stream);
    fused_mha<<<512, 512, 0, stream>>>(q, Wq, bq, Wkv, bkv, Wo, bo,
                                       qb, WT, QKVbuf, VtG, AObuf, out, bar);
}